// Round 4
// baseline (70.335 us; speedup 1.0000x reference)
//
#include <hip/hip_runtime.h>
#include <math.h>

// Problem constants (fixed by the reference setup)
constexpr int NN   = 128;  // instances
constexpr int CC   = 80;   // classes
constexpr int MM   = 28;   // mask resolution
constexpr int HH   = 768;  // scene height
constexpr int WW   = 768;  // scene width
constexpr int NUMV = 80;   // NUM_VALID

constexpr int WAVES  = 4;            // 256 threads
constexpr int RPW    = 4;            // rows per wave
constexpr int ROWS   = WAVES * RPW;  // 16 rows per block
constexpr int YGRP   = HH / ROWS;    // 48 row-groups per instance
constexpr int F4ROW  = WW / 4;       // 192 float4 per row
constexpr int ITROW  = F4ROW / 64;   // 3 float4-iterations per row per lane

// Native clang vector type — required by __builtin_nontemporal_store.
typedef float f32x4 __attribute__((ext_vector_type(4)));

// Single-pass kernel: every output element written exactly once.
// Each WAVE owns whole rows (64 lanes x float4 = 1KB contiguous per store
// instruction; 3 per row). Row-active is wave-uniform -> no divergence
// between rows within a wave; y-interp math is wave-uniform scalar.
__global__ __launch_bounds__(256)
void fused_paste_kernel(const float* __restrict__ mask_output,
                        const int*   __restrict__ class_indices,
                        const float* __restrict__ bbox,
                        f32x4*       __restrict__ out4) {
    const int bid  = blockIdx.x;
    const int n    = bid / YGRP;
    const int yg   = bid - n * YGRP;
    const int wave = threadIdx.x >> 6;   // 0..3
    const int lane = threadIdx.x & 63;   // 64 lanes cover a row in 3 steps

    const int  ci    = class_indices[n];
    const bool valid = (ci >= 0) & (ci < NUMV);

    float x0 = 0.f, y0 = 0.f, x1 = 1.f, y1 = 1.f;
    float sx = 0.f, sy = 0.f;
    int ybeg = HH, yend = 0, xbeg = 0, xend = 0;
    const float* __restrict__ mb = mask_output;
    if (valid) {
        x0 = bbox[n * 4 + 0];
        y0 = bbox[n * 4 + 1];
        x1 = bbox[n * 4 + 2];
        y1 = bbox[n * 4 + 3];
        sx = (float)MM / (x1 - x0);
        sy = (float)MM / (y1 - y0);
        const float ex = (x1 - x0) / (2.0f * (float)MM);
        const float ey = (y1 - y0) / (2.0f * (float)MM);
        ybeg = max(0,  (int)floorf(y0 - ey - 0.5f));
        yend = min(HH, (int)ceilf (y1 + ey + 0.5f) + 1);
        xbeg = max(0,  (int)floorf(x0 - ex - 0.5f));
        xend = min(WW, (int)ceilf (x1 + ex + 0.5f) + 1);
        mb = mask_output + ((size_t)n * CC + ci) * (MM * MM);
    }

    const int ybase = yg * ROWS + wave * RPW;

    #pragma unroll
    for (int rr = 0; rr < RPW; ++rr) {
        const int y = ybase + rr;
        f32x4* __restrict__ orow = out4 + ((size_t)n * HH + y) * F4ROW;

        const bool rowActive = valid & (y >= ybeg) & (y < yend);
        if (!rowActive) {
            const f32x4 z = (f32x4)(0.0f);
            #pragma unroll
            for (int it = 0; it < ITROW; ++it)
                __builtin_nontemporal_store(z, &orow[lane + it * 64]);
            continue;
        }

        // ---- active row (wave-uniform y math) ----
        const float gy  = ((float)y + 0.5f - y0) * sy - 0.5f;
        const float fy  = floorf(gy);
        const int   iy0 = (int)fy;
        const int   iy1 = iy0 + 1;
        float wy1 = gy - fy;
        float wy0 = 1.0f - wy1;
        if (iy0 < 0 || iy0 >= MM) wy0 = 0.0f;
        if (iy1 < 0 || iy1 >= MM) wy1 = 0.0f;
        const int cy0 = min(max(iy0, 0), MM - 1);
        const int cy1 = min(max(iy1, 0), MM - 1);
        const float* __restrict__ r0 = mb + cy0 * MM;
        const float* __restrict__ r1 = mb + cy1 * MM;

        #pragma unroll
        for (int it = 0; it < ITROW; ++it) {
            const int c4 = lane + it * 64;
            const int xb = c4 * 4;
            f32x4 v = (f32x4)(0.0f);
            if (xb + 3 >= xbeg && xb < xend) {
                #pragma unroll
                for (int j = 0; j < 4; ++j) {
                    const int   x   = xb + j;
                    const float gx  = ((float)x + 0.5f - x0) * sx - 0.5f;
                    const float fx  = floorf(gx);
                    const int   ix0 = (int)fx;
                    const int   ix1 = ix0 + 1;
                    float wx1 = gx - fx;
                    float wx0 = 1.0f - wx1;
                    if (ix0 < 0 || ix0 >= MM) wx0 = 0.0f;
                    if (ix1 < 0 || ix1 >= MM) wx1 = 0.0f;
                    const int cx0 = min(max(ix0, 0), MM - 1);
                    const int cx1 = min(max(ix1, 0), MM - 1);

                    // sigmoid BEFORE interpolation (matches reference)
                    const float s00 = 1.0f / (1.0f + __expf(-r0[cx0]));
                    const float s01 = 1.0f / (1.0f + __expf(-r0[cx1]));
                    const float s10 = 1.0f / (1.0f + __expf(-r1[cx0]));
                    const float s11 = 1.0f / (1.0f + __expf(-r1[cx1]));

                    v[j] = wy0 * (wx0 * s00 + wx1 * s01) +
                           wy1 * (wx0 * s10 + wx1 * s11);
                }
            }
            __builtin_nontemporal_store(v, &orow[c4]);
        }
    }
}

extern "C" void kernel_launch(void* const* d_in, const int* in_sizes, int n_in,
                              void* d_out, int out_size, void* d_ws, size_t ws_size,
                              hipStream_t stream) {
    const float* mask = (const float*)d_in[0];
    const int*   cls  = (const int*)  d_in[1];
    const float* bbox = (const float*)d_in[2];
    f32x4*       out4 = (f32x4*)d_out;

    // Single pass: 128 instances x 48 row-groups; each block writes 16 full
    // rows (48KB) exactly once, wave-per-row coalesced.
    fused_paste_kernel<<<NN * YGRP, 256, 0, stream>>>(mask, cls, bbox, out4);
}

// Round 5
// 47.090 us; speedup vs baseline: 1.4936x; 1.4936x over previous
//
#include <hip/hip_runtime.h>
#include <math.h>

// Problem constants (fixed by the reference setup)
constexpr int NN   = 128;  // instances
constexpr int CC   = 80;   // classes
constexpr int MM   = 28;   // mask resolution
constexpr int HH   = 768;  // scene height
constexpr int WW   = 768;  // scene width
constexpr int NUMV = 80;   // NUM_VALID

constexpr int ROWS = 8;           // rows per block (256 thr = 8 rows x 32 lanes)
constexpr int YGRP = HH / ROWS;   // 96 row-groups per instance
constexpr int IT   = WW / 4 / 32; // 6 float4-iterations per row per lane

typedef float f32x4 __attribute__((ext_vector_type(4)));

// Single-pass kernel (R3 structure): every output element written exactly
// once. PLAIN stores (not nontemporal): the 302MB output nearly fits the
// 256MB Infinity Cache, so cached stores let L3 absorb most write traffic
// across graph replays instead of forcing every byte to HBM.
__global__ __launch_bounds__(256)
void fused_paste_kernel(const float* __restrict__ mask_output,
                        const int*   __restrict__ class_indices,
                        const float* __restrict__ bbox,
                        f32x4*       __restrict__ out4) {
    const int bid  = blockIdx.x;
    const int n    = bid / YGRP;
    const int yg   = bid - n * YGRP;
    const int r    = threadIdx.x >> 5;   // row within group: 0..7
    const int lane = threadIdx.x & 31;   // 32 lanes cover a row in 6 steps
    const int y    = yg * ROWS + r;

    f32x4* __restrict__ orow = out4 + ((size_t)n * HH + y) * (WW / 4);

    const int  ci    = class_indices[n];
    const bool valid = (ci >= 0) & (ci < NUMV);

    bool  rowActive = false;
    float x0 = 0.f, y0 = 0.f, x1 = 1.f, y1 = 1.f;
    if (valid) {
        x0 = bbox[n * 4 + 0];
        y0 = bbox[n * 4 + 1];
        x1 = bbox[n * 4 + 2];
        y1 = bbox[n * 4 + 3];
        const float ey   = (y1 - y0) / (2.0f * (float)MM);
        const int   ybeg = max(0,  (int)floorf(y0 - ey - 0.5f));
        const int   yend = min(HH, (int)ceilf (y1 + ey + 0.5f) + 1);
        rowActive = (y >= ybeg) & (y < yend);
    }

    if (!rowActive) {
        const f32x4 z = (f32x4)(0.0f);
        #pragma unroll
        for (int it = 0; it < IT; ++it)
            orow[lane + it * 32] = z;
        return;
    }

    // ---- active row ----
    const float sx = (float)MM / (x1 - x0);
    const float sy = (float)MM / (y1 - y0);
    const float ex = (x1 - x0) / (2.0f * (float)MM);
    const int xbeg = max(0,  (int)floorf(x0 - ex - 0.5f));
    const int xend = min(WW, (int)ceilf (x1 + ex + 0.5f) + 1);

    const float gy  = ((float)y + 0.5f - y0) * sy - 0.5f;
    const float fy  = floorf(gy);
    const int   iy0 = (int)fy;
    const int   iy1 = iy0 + 1;
    float wy1 = gy - fy;
    float wy0 = 1.0f - wy1;
    if (iy0 < 0 || iy0 >= MM) wy0 = 0.0f;
    if (iy1 < 0 || iy1 >= MM) wy1 = 0.0f;
    const int cy0 = min(max(iy0, 0), MM - 1);
    const int cy1 = min(max(iy1, 0), MM - 1);

    const float* __restrict__ mb = mask_output + ((size_t)n * CC + ci) * (MM * MM);
    const float* __restrict__ r0 = mb + cy0 * MM;
    const float* __restrict__ r1 = mb + cy1 * MM;

    #pragma unroll
    for (int it = 0; it < IT; ++it) {
        const int c4 = lane + it * 32;
        const int xb = c4 * 4;
        f32x4 v = (f32x4)(0.0f);
        if (xb + 3 >= xbeg && xb < xend) {
            #pragma unroll
            for (int j = 0; j < 4; ++j) {
                const int   x   = xb + j;
                const float gx  = ((float)x + 0.5f - x0) * sx - 0.5f;
                const float fx  = floorf(gx);
                const int   ix0 = (int)fx;
                const int   ix1 = ix0 + 1;
                float wx1 = gx - fx;
                float wx0 = 1.0f - wx1;
                if (ix0 < 0 || ix0 >= MM) wx0 = 0.0f;
                if (ix1 < 0 || ix1 >= MM) wx1 = 0.0f;
                const int cx0 = min(max(ix0, 0), MM - 1);
                const int cx1 = min(max(ix1, 0), MM - 1);

                // sigmoid BEFORE interpolation (matches reference)
                const float s00 = 1.0f / (1.0f + __expf(-r0[cx0]));
                const float s01 = 1.0f / (1.0f + __expf(-r0[cx1]));
                const float s10 = 1.0f / (1.0f + __expf(-r1[cx0]));
                const float s11 = 1.0f / (1.0f + __expf(-r1[cx1]));

                v[j] = wy0 * (wx0 * s00 + wx1 * s01) +
                       wy1 * (wx0 * s10 + wx1 * s11);
            }
        }
        orow[c4] = v;
    }
}

extern "C" void kernel_launch(void* const* d_in, const int* in_sizes, int n_in,
                              void* d_out, int out_size, void* d_ws, size_t ws_size,
                              hipStream_t stream) {
    const float* mask = (const float*)d_in[0];
    const int*   cls  = (const int*)  d_in[1];
    const float* bbox = (const float*)d_in[2];
    f32x4*       out4 = (f32x4*)d_out;

    // Single pass: 128 instances x 96 row-groups; each block writes 8 full
    // rows (zeros or pasted values) exactly once. Plain (cached) stores.
    fused_paste_kernel<<<NN * YGRP, 256, 0, stream>>>(mask, cls, bbox, out4);
}